// Round 1
// baseline (1014.430 us; speedup 1.0000x reference)
//
#include <hip/hip_runtime.h>

#define U_N 8192
#define I_N 16384

typedef float f4 __attribute__((ext_vector_type(4)));
typedef unsigned long long u64;

#if defined(__has_builtin)
#if __has_builtin(__builtin_amdgcn_cvt_pk_fp8_f32)
#define HAS_HW_FP8 1
#endif
#endif
#ifndef HAS_HW_FP8
#define HAS_HW_FP8 0
#endif

// float -> OCP e4m3fn byte, RTNE, saturating. Software fallback version.
__device__ __forceinline__ unsigned char f2e4m3_soft(float x) {
  unsigned char sign = (x < 0.f) ? 0x80 : 0x00;
  float ax = fabsf(x);
  unsigned char code;
  if (ax >= 448.f) {
    code = 0x7E;
  } else if (ax < 0.015625f) {
    int q = (int)rintf(ax * 512.f);
    code = (unsigned char)q;
  } else {
    int e; float f = frexpf(ax, &e);
    int q = (int)rintf(f * 16.f);
    if (q == 16) { q = 8; e += 1; }
    code = (unsigned char)(((e + 6) << 3) | (q - 8));
  }
  return sign | code;
}

// single-value quantize (HW when available)
__device__ __forceinline__ unsigned char q8(float x) {
#if HAS_HW_FP8
  return (unsigned char)(__builtin_amdgcn_cvt_pk_fp8_f32(x, 0.f, 0, false) & 0xff);
#else
  return f2e4m3_soft(x);
#endif
}

// pack 4 floats -> 4 fp8 bytes in one dword (byte0 = a)
__device__ __forceinline__ unsigned int pack4_fp8(float a, float b, float c, float d) {
#if HAS_HW_FP8
  int v = __builtin_amdgcn_cvt_pk_fp8_f32(a, b, 0, false);
  v = __builtin_amdgcn_cvt_pk_fp8_f32(c, d, v, true);
  return (unsigned int)v;
#else
  return (unsigned)f2e4m3_soft(a) | ((unsigned)f2e4m3_soft(b) << 8) |
         ((unsigned)f2e4m3_soft(c) << 16) | ((unsigned)f2e4m3_soft(d) << 24);
#endif
}

// Scales: S * 2^17 (max 16), u0/i0 * 2^9 (max ~14), propagated vectors * 2^16.
#define SCALE_S   131072.f
#define SCALE_V0  512.f
#define SCALE_VK  65536.f

// ---------------------------------------------------------------------------
// convert: u0 -> wT0[e][r], i0 -> vT0[e][c], and (f8 path) S fp32 ->
//   S8  [8192][16384] fp8 row-major
//   S8T [16384][8192] fp8 (transpose), via 64x64 register+LDS tile transpose
// grid: 1024 (u0) + 2048 (i0) + 32768 (64x64 S tiles) when f8
// ---------------------------------------------------------------------------
__global__ __launch_bounds__(256)
void convert_kernel(const float* __restrict__ Sf,
                    const float* __restrict__ u0,
                    const float* __restrict__ i0,
                    unsigned char* __restrict__ S8,
                    unsigned char* __restrict__ S8T,
                    unsigned char* __restrict__ wT0,
                    unsigned char* __restrict__ vT0)
{
  const int tid = threadIdx.x;
  const int bid = blockIdx.x;
  if (bid < 1024) {
    const int idx = bid * 256 + tid;                 // over U_N*32
    wT0[(idx & 31) * U_N + (idx >> 5)] = q8(u0[idx] * SCALE_V0);
  } else if (bid < 3072) {
    const int idx = (bid - 1024) * 256 + tid;        // over I_N*32
    vT0[(idx & 31) * I_N + (idx >> 5)] = q8(i0[idx] * SCALE_V0);
  } else {
    // 64x64 tile: thread owns a 4x4 micro-tile. Reads Sf coalesced (float4),
    // writes S8 rows coalesced (dword), and builds column dwords for the
    // transpose, staged through LDS (stride 68 = conflict-light, dword ops).
    __shared__ unsigned char lds[64 * 68];
    const int b = bid - 3072;
    const int tr = b >> 8;                 // 0..127 row tile
    const int tc = b & 255;                // 0..255 col tile
    const int mr = (tid >> 4) << 2;        // 0..60
    const int mc = (tid & 15) << 2;        // 0..60
    const size_t base = ((size_t)tr * 64 + mr) * I_N + (size_t)tc * 64 + mc;
    float fs[4][4];
#pragma unroll
    for (int i = 0; i < 4; ++i) {
      float4 f = *(const float4*)(Sf + base + (size_t)i * I_N);
      fs[i][0] = f.x * SCALE_S; fs[i][1] = f.y * SCALE_S;
      fs[i][2] = f.z * SCALE_S; fs[i][3] = f.w * SCALE_S;
    }
#pragma unroll
    for (int i = 0; i < 4; ++i)
      *(unsigned int*)&S8[base + (size_t)i * I_N] =
          pack4_fp8(fs[i][0], fs[i][1], fs[i][2], fs[i][3]);
#pragma unroll
    for (int j = 0; j < 4; ++j)
      *(unsigned int*)&lds[(mc + j) * 68 + mr] =
          pack4_fp8(fs[0][j], fs[1][j], fs[2][j], fs[3][j]);
    __syncthreads();
    const int c = tid >> 2;                // 0..63 (row of S8T tile)
    const int s = (tid & 3) << 4;          // 0,16,32,48
    uint4 v;
    v.x = *(const unsigned int*)&lds[c * 68 + s];
    v.y = *(const unsigned int*)&lds[c * 68 + s + 4];
    v.z = *(const unsigned int*)&lds[c * 68 + s + 8];
    v.w = *(const unsigned int*)&lds[c * 68 + s + 12];
    *(uint4*)&S8T[((size_t)tc * 64 + c) * U_N + (size_t)tr * 64 + s] = v;
  }
}

// ---------------------------------------------------------------------------
// unified half-GEMM: part[ksplit][r][e] = sum_{k in split} A[r][k] * Bt[e][k]
// A row-major fp8 [nrows][kdim]; Bt = B^T fp8 [32][kdim].
// Block: 64 rows x 2048-k stripe, 4 chunks of 512; wave w owns rows +16*w.
// A-frag: lane holds A[m=lane&15][quad*8+j] via direct 8B global load.
// B-frag: smem[e*528 + k], lane reads e=m / e=m+16.
// D: col=lane&15, row=quad*4+reg.
// ---------------------------------------------------------------------------
__device__ __forceinline__ void half_gemm(
    const unsigned char* __restrict__ A,
    const unsigned char* __restrict__ Bt,
    float* __restrict__ part,
    unsigned char* smem,
    int rgroup, int ksplit, int nrows, size_t kdim, float descale, int tid)
{
  const int lane = tid & 63;
  const int wave = tid >> 6;
  const int m = lane & 15;
  const int quad = lane >> 4;
  const int r0 = rgroup * 64 + wave * 16;
  const int kbase = ksplit * 2048;
  f4 acc0 = {0.f, 0.f, 0.f, 0.f};
  f4 acc1 = {0.f, 0.f, 0.f, 0.f};
  for (int ch = 0; ch < 4; ++ch) {
    const int kb = kbase + ch * 512;
    // stage Bt[32][kb..kb+512] -> smem[e*528 + x]
#pragma unroll
    for (int it = 0; it < 4; ++it) {
      const int idx = it * 256 + tid;
      const int e = idx >> 5;
      const int o = (idx & 31) * 16;
      *(uint4*)&smem[e * 528 + o] = *(const uint4*)&Bt[(size_t)e * kdim + kb + o];
    }
    __syncthreads();
#pragma unroll
    for (int kk = 0; kk < 512; kk += 32) {
      const long a  = *(const long*)(A + (size_t)(r0 + m) * kdim + kb + kk + quad * 8);
      const long b0 = *(const long*)&smem[m * 528 + kk + quad * 8];
      const long b1 = *(const long*)&smem[(m + 16) * 528 + kk + quad * 8];
      acc0 = __builtin_amdgcn_mfma_f32_16x16x32_fp8_fp8(a, b0, acc0, 0, 0, 0);
      acc1 = __builtin_amdgcn_mfma_f32_16x16x32_fp8_fp8(a, b1, acc1, 0, 0, 0);
    }
    __syncthreads();
  }
  float* dst = part + (size_t)ksplit * ((size_t)nrows * 32);
#pragma unroll
  for (int i2 = 0; i2 < 4; ++i2) {
    const int r = r0 + quad * 4 + i2;
    dst[r * 32 + m]      = acc0[i2] * descale;
    dst[r * 32 + 16 + m] = acc1[i2] * descale;
  }
}

// f8 fast path: both products per round, both structurally identical.
//   blocks [0,1024):    u_part[ks][r][e], A=S8  (128 rgroups x 8 ksplits)
//   blocks [1024,2048): i_part[rs][c][e], A=S8T (256 rgroups x 4 ksplits)
__global__ __launch_bounds__(256, 4)
void pass_kernel(const unsigned char* __restrict__ S8,
                 const unsigned char* __restrict__ S8T,
                 const unsigned char* __restrict__ vT,
                 const unsigned char* __restrict__ wT,
                 float* __restrict__ u_part,
                 float* __restrict__ i_part,
                 float descale)
{
  __shared__ unsigned char smem[16896];
  const int bid = blockIdx.x;
  if (bid < 1024) {
    half_gemm(S8, vT, u_part, smem, bid & 127, bid >> 7, U_N, (size_t)I_N,
              descale, threadIdx.x);
  } else {
    const int b = bid - 1024;
    half_gemm(S8T, wT, i_part, smem, b & 255, b >> 8, I_N, (size_t)U_N,
              descale, threadIdx.x);
  }
}

// ---------------------------------------------------------------------------
// fallback pass (small workspace): original Sf-based kernel, on-the-fly quant
// ---------------------------------------------------------------------------
__global__ __launch_bounds__(256, 4)
void pass_fallback(const float* __restrict__ Sf,
                   const unsigned char* __restrict__ vT,
                   const unsigned char* __restrict__ wT,
                   float* __restrict__ u_part,
                   float* __restrict__ i_part,
                   float descale)
{
  __shared__ unsigned char smem[16896];
  const int tid = threadIdx.x;
  const int lane = tid & 63;
  const int wave = tid >> 6;
  const int m = lane & 15;
  const int quad = lane >> 4;
  const int bid = blockIdx.x;

  if (bid < 1024) {
    const int rg = bid & 127, ks = bid >> 7;
    const int r0 = rg * 64 + wave * 16;
    const int cbase = ks * 2048;
    f4 acc0 = {0.f, 0.f, 0.f, 0.f};
    f4 acc1 = {0.f, 0.f, 0.f, 0.f};
    for (int ch = 0; ch < 4; ++ch) {
      const int cb = cbase + ch * 512;
#pragma unroll
      for (int it = 0; it < 4; ++it) {
        const int idx = it * 256 + tid;
        const int e = idx >> 5;
        const int o = (idx & 31) * 16;
        *(uint4*)&smem[e * 528 + o] = *(const uint4*)&vT[(size_t)e * I_N + cb + o];
      }
      __syncthreads();
#pragma unroll
      for (int kk = 0; kk < 512; kk += 32) {
        const float* p = Sf + (size_t)(r0 + m) * I_N + cb + kk + quad * 8;
        u64 av = 0;
#pragma unroll
        for (int j = 0; j < 8; ++j) av |= (u64)q8(p[j] * SCALE_S) << (8 * j);
        const long a = (long)av;
        const long b0 = *(const long*)&smem[m * 528 + kk + quad * 8];
        const long b1 = *(const long*)&smem[(m + 16) * 528 + kk + quad * 8];
        acc0 = __builtin_amdgcn_mfma_f32_16x16x32_fp8_fp8(a, b0, acc0, 0, 0, 0);
        acc1 = __builtin_amdgcn_mfma_f32_16x16x32_fp8_fp8(a, b1, acc1, 0, 0, 0);
      }
      __syncthreads();
    }
    float* dst = u_part + (size_t)ks * (U_N * 32);
#pragma unroll
    for (int i2 = 0; i2 < 4; ++i2) {
      const int r = r0 + quad * 4 + i2;
      dst[r * 32 + m]      = acc0[i2] * descale;
      dst[r * 32 + 16 + m] = acc1[i2] * descale;
    }
  } else {
    const int b = bid - 1024;
    const int cg = b & 255, rs = b >> 8;
    const int c0 = cg * 64;
    const int rbase = rs * 2048;
    const int cw = wave * 16;
    unsigned char* stile = smem;
    unsigned char* wlds  = smem + 9216;
    f4 acc0 = {0.f, 0.f, 0.f, 0.f};
    f4 acc1 = {0.f, 0.f, 0.f, 0.f};
    for (int ch = 0; ch < 16; ++ch) {
      const int rb = rbase + ch * 128;
#pragma unroll
      for (int it = 0; it < 4; ++it) {
        const int idx = it * 256 + tid;
        const int rr = idx >> 3;
        const int o = (idx & 7) * 8;
        const float* p = Sf + (size_t)(rb + rr) * I_N + c0 + o;
        u64 v = 0;
#pragma unroll
        for (int j = 0; j < 8; ++j) v |= (u64)q8(p[j] * SCALE_S) << (8 * j);
        *(u64*)&stile[rr * 72 + o] = v;
      }
      {
        const int e = tid >> 3;
        const int o = (tid & 7) * 16;
        *(uint4*)&wlds[e * 144 + o] = *(const uint4*)&wT[(size_t)e * U_N + rb + o];
      }
      __syncthreads();
#pragma unroll
      for (int kk = 0; kk < 128; kk += 32) {
        u64 av = 0;
#pragma unroll
        for (int j = 0; j < 8; ++j)
          av |= (u64)stile[(kk + quad * 8 + j) * 72 + cw + m] << (8 * j);
        const long b0 = *(const long*)&wlds[m * 144 + kk + quad * 8];
        const long b1 = *(const long*)&wlds[(m + 16) * 144 + kk + quad * 8];
        acc0 = __builtin_amdgcn_mfma_f32_16x16x32_fp8_fp8((long)av, b0, acc0, 0, 0, 0);
        acc1 = __builtin_amdgcn_mfma_f32_16x16x32_fp8_fp8((long)av, b1, acc1, 0, 0, 0);
      }
      __syncthreads();
    }
    float* dst = i_part + (size_t)rs * (I_N * 32);
#pragma unroll
    for (int i2 = 0; i2 < 4; ++i2) {
      const int c = c0 + cw + quad * 4 + i2;
      dst[c * 32 + m]      = acc0[i2] * descale;
      dst[c * 32 + 16 + m] = acc1[i2] * descale;
    }
  }
}

// ---------------------------------------------------------------------------
// reduce: sum split-K partials, fp32 running sums, re-quantize next vectors,
// round 3 writes outputs. grid: 3072 x 256 == U_N*32 + I_N*32 threads
// ---------------------------------------------------------------------------
__global__ __launch_bounds__(256)
void reduce_kernel(const float* __restrict__ u_part, const float* __restrict__ i_part,
                   const float* __restrict__ u0, const float* __restrict__ i0,
                   float* __restrict__ acc_u, float* __restrict__ acc_i,
                   unsigned char* __restrict__ wT, unsigned char* __restrict__ vT,
                   float* __restrict__ out_u, float* __restrict__ out_i,
                   int round)
{
  const int gid = blockIdx.x * 256 + threadIdx.x;
  if (gid < U_N * 32) {
    float s = 0.f;
#pragma unroll
    for (int sp = 0; sp < 8; ++sp) s += u_part[(size_t)sp * (U_N * 32) + gid];
    if (round == 1)      acc_u[gid] = u0[gid] + s;
    else if (round == 2) acc_u[gid] += s;
    else                 out_u[gid] = (acc_u[gid] + s) * 0.25f;
    if (round < 3) wT[(gid & 31) * U_N + (gid >> 5)] = q8(s * SCALE_VK);
  } else {
    const int g = gid - U_N * 32;
    float s = 0.f;
#pragma unroll
    for (int sp = 0; sp < 4; ++sp) s += i_part[(size_t)sp * (I_N * 32) + g];
    if (round == 1)      acc_i[g] = i0[g] + s;
    else if (round == 2) acc_i[g] += s;
    else                 out_i[g] = (acc_i[g] + s) * 0.25f;
    if (round < 3) vT[(g & 31) * I_N + (g >> 5)] = q8(s * SCALE_VK);
  }
}

extern "C" void kernel_launch(void* const* d_in, const int* in_sizes, int n_in,
                              void* d_out, int out_size, void* d_ws, size_t ws_size,
                              hipStream_t stream) {
  const float* u0 = (const float*)d_in[0];   // [8192][32]
  const float* i0 = (const float*)d_in[1];   // [16384][32]
  const float* Sf = (const float*)d_in[2];   // [8192][16384]
  float* out_u = (float*)d_out;
  float* out_i = out_u + U_N * 32;
  unsigned char* ws = (unsigned char*)d_ws;

  const size_t S8_BYTES = (size_t)U_N * I_N;        // 128 MB each
  const size_t SMALL_BYTES = 20709376;              // partials + accs + vTs
  const bool f8 = ws_size >= 2 * S8_BYTES + SMALL_BYTES;

  unsigned char* S8 = nullptr;
  unsigned char* S8T = nullptr;
  unsigned char* cur;
  if (f8) { S8 = ws; S8T = ws + S8_BYTES; cur = ws + 2 * S8_BYTES; }
  else    { cur = ws; }
  float* u_part = (float*)cur;                      // 8 * U_N*32 floats
  float* i_part = u_part + 8 * U_N * 32;            // 4 * I_N*32 floats
  float* acc_u  = i_part + 4 * I_N * 32;
  float* acc_i  = acc_u + U_N * 32;
  unsigned char* wT = (unsigned char*)(acc_i + I_N * 32);   // 32*U_N bytes
  unsigned char* vT = wT + 32 * U_N;                        // 32*I_N bytes

  convert_kernel<<<f8 ? 35840 : 3072, 256, 0, stream>>>(Sf, u0, i0, S8, S8T, wT, vT);

  const float ds1 = 1.f / (SCALE_S * SCALE_V0);
  const float dsk = 1.f / (SCALE_S * SCALE_VK);
  for (int round = 1; round <= 3; ++round) {
    const float ds = (round == 1) ? ds1 : dsk;
    if (f8)
      pass_kernel<<<2048, 256, 0, stream>>>(S8, S8T, vT, wT, u_part, i_part, ds);
    else
      pass_fallback<<<2048, 256, 0, stream>>>(Sf, vT, wT, u_part, i_part, ds);
    reduce_kernel<<<3072, 256, 0, stream>>>(u_part, i_part, u0, i0, acc_u, acc_i,
                                            wT, vT, out_u, out_i, round);
  }
}

// Round 2
// 921.581 us; speedup vs baseline: 1.1007x; 1.1007x over previous
//
#include <hip/hip_runtime.h>

#define U_N 8192
#define I_N 16384

typedef float f4 __attribute__((ext_vector_type(4)));
typedef unsigned long long u64;
typedef unsigned char u8;

#if defined(__has_builtin)
#if __has_builtin(__builtin_amdgcn_cvt_pk_fp8_f32)
#define HAS_HW_FP8 1
#endif
#endif
#ifndef HAS_HW_FP8
#define HAS_HW_FP8 0
#endif

// float -> OCP e4m3fn byte, RTNE, saturating. Software fallback version.
__device__ __forceinline__ unsigned char f2e4m3_soft(float x) {
  unsigned char sign = (x < 0.f) ? 0x80 : 0x00;
  float ax = fabsf(x);
  unsigned char code;
  if (ax >= 448.f) {
    code = 0x7E;
  } else if (ax < 0.015625f) {
    int q = (int)rintf(ax * 512.f);
    code = (unsigned char)q;
  } else {
    int e; float f = frexpf(ax, &e);
    int q = (int)rintf(f * 16.f);
    if (q == 16) { q = 8; e += 1; }
    code = (unsigned char)(((e + 6) << 3) | (q - 8));
  }
  return sign | code;
}

__device__ __forceinline__ unsigned char q8(float x) {
#if HAS_HW_FP8
  return (unsigned char)(__builtin_amdgcn_cvt_pk_fp8_f32(x, 0.f, 0, false) & 0xff);
#else
  return f2e4m3_soft(x);
#endif
}

__device__ __forceinline__ unsigned int pack4_fp8(float a, float b, float c, float d) {
#if HAS_HW_FP8
  int v = __builtin_amdgcn_cvt_pk_fp8_f32(a, b, 0, false);
  v = __builtin_amdgcn_cvt_pk_fp8_f32(c, d, v, true);
  return (unsigned int)v;
#else
  return (unsigned)f2e4m3_soft(a) | ((unsigned)f2e4m3_soft(b) << 8) |
         ((unsigned)f2e4m3_soft(c) << 16) | ((unsigned)f2e4m3_soft(d) << 24);
#endif
}

// Scales: S * 2^17 (max 16), u0/i0 * 2^9, propagated vectors * 2^16.
#define SCALE_S   131072.f
#define SCALE_V0  512.f
#define SCALE_VK  65536.f

// ---------------------------------------------------------------------------
// convert: u0 -> wT rows 0..31 (of a [64][U_N] buffer), i0 -> vT0[32][I_N],
// and (f8 path) S -> S8 row-major + S8T transposed via 64x64 LDS tiles.
// ---------------------------------------------------------------------------
__global__ __launch_bounds__(256)
void convert_kernel(const float* __restrict__ Sf,
                    const float* __restrict__ u0,
                    const float* __restrict__ i0,
                    u8* __restrict__ S8,
                    u8* __restrict__ S8T,
                    u8* __restrict__ wT0,
                    u8* __restrict__ vT0)
{
  const int tid = threadIdx.x;
  const int bid = blockIdx.x;
  if (bid < 1024) {
    const int idx = bid * 256 + tid;                 // over U_N*32
    wT0[(size_t)(idx & 31) * U_N + (idx >> 5)] = q8(u0[idx] * SCALE_V0);
  } else if (bid < 3072) {
    const int idx = (bid - 1024) * 256 + tid;        // over I_N*32
    vT0[(size_t)(idx & 31) * I_N + (idx >> 5)] = q8(i0[idx] * SCALE_V0);
  } else {
    __shared__ unsigned char lds[64 * 68];
    const int b = bid - 3072;
    const int tr = b >> 8;                 // 0..127 row tile
    const int tc = b & 255;                // 0..255 col tile
    const int mr = (tid >> 4) << 2;
    const int mc = (tid & 15) << 2;
    const size_t base = ((size_t)tr * 64 + mr) * I_N + (size_t)tc * 64 + mc;
    float fs[4][4];
#pragma unroll
    for (int i = 0; i < 4; ++i) {
      float4 f = *(const float4*)(Sf + base + (size_t)i * I_N);
      fs[i][0] = f.x * SCALE_S; fs[i][1] = f.y * SCALE_S;
      fs[i][2] = f.z * SCALE_S; fs[i][3] = f.w * SCALE_S;
    }
#pragma unroll
    for (int i = 0; i < 4; ++i)
      *(unsigned int*)&S8[base + (size_t)i * I_N] =
          pack4_fp8(fs[i][0], fs[i][1], fs[i][2], fs[i][3]);
#pragma unroll
    for (int j = 0; j < 4; ++j)
      *(unsigned int*)&lds[(mc + j) * 68 + mr] =
          pack4_fp8(fs[0][j], fs[1][j], fs[2][j], fs[3][j]);
    __syncthreads();
    const int c = tid >> 2;
    const int s = (tid & 3) << 4;
    uint4 v;
    v.x = *(const unsigned int*)&lds[c * 68 + s];
    v.y = *(const unsigned int*)&lds[c * 68 + s + 4];
    v.z = *(const unsigned int*)&lds[c * 68 + s + 8];
    v.w = *(const unsigned int*)&lds[c * 68 + s + 12];
    *(uint4*)&S8T[((size_t)tc * 64 + c) * U_N + (size_t)tr * 64 + s] = v;
  }
}

// ---------------------------------------------------------------------------
// sweep: part[ksplit][r][0..NE) = sum_{k in split} A[r][k] * Bt[e][k]
// A fp8 [nrows][kdim]; Bt fp8 [NE][kdim]. 64 rows x 2048-K per block.
// 16B A-loads cover TWO MFMA k-steps via consistent k-permutation:
// both A and B use offset quad*16, halves l[0]/l[1] feed the two MFMAs
// (k-blocks are permuted identically on A and B, so the sum is exact).
// ---------------------------------------------------------------------------
union B16 { uint4 v; long l[2]; };

template <int NE>
__global__ __launch_bounds__(256, 4)
void sweep_kernel(const u8* __restrict__ A, const u8* __restrict__ Bt,
                  float* __restrict__ part, int rg_mask, int rg_shift,
                  int nrows, int kdim, float ds_lo, float ds_hi)
{
  __shared__ u8 smem[NE * 528];
  const int tid = threadIdx.x;
  const int lane = tid & 63, wave = tid >> 6;
  const int m = lane & 15, quad = lane >> 4;
  const int bid = blockIdx.x;
  const int rgroup = bid & rg_mask, ksplit = bid >> rg_shift;
  const int r0 = rgroup * 64 + wave * 16;
  const int kbase = ksplit * 2048;
  f4 acc[NE / 16];
#pragma unroll
  for (int eb = 0; eb < NE / 16; ++eb) acc[eb] = {0.f, 0.f, 0.f, 0.f};

  const u8* arow = A + (size_t)(r0 + m) * kdim;

  for (int ch = 0; ch < 4; ++ch) {
    const int kb = kbase + ch * 512;
    // stage Bt[NE][kb..kb+512] -> smem[e*528 + x]
#pragma unroll
    for (int it = 0; it < NE / 8; ++it) {
      const int idx = it * 256 + tid;
      const int e = idx >> 5;
      const int o = (idx & 31) * 16;
      *(uint4*)&smem[e * 528 + o] = *(const uint4*)&Bt[(size_t)e * kdim + kb + o];
    }
    __syncthreads();
#pragma unroll
    for (int pr = 0; pr < 8; ++pr) {
      B16 av;
      av.v = *(const uint4*)(arow + kb + pr * 64 + quad * 16);
#pragma unroll
      for (int eb = 0; eb < NE / 16; ++eb) {
        B16 bv;
        bv.v = *(const uint4*)&smem[(m + eb * 16) * 528 + pr * 64 + quad * 16];
        acc[eb] = __builtin_amdgcn_mfma_f32_16x16x32_fp8_fp8(av.l[0], bv.l[0], acc[eb], 0, 0, 0);
        acc[eb] = __builtin_amdgcn_mfma_f32_16x16x32_fp8_fp8(av.l[1], bv.l[1], acc[eb], 0, 0, 0);
      }
    }
    __syncthreads();
  }
  float* dst = part + (size_t)ksplit * ((size_t)nrows * NE);
#pragma unroll
  for (int eb = 0; eb < NE / 16; ++eb) {
    const float ds = (eb < 2) ? ds_lo : ds_hi;
#pragma unroll
    for (int i2 = 0; i2 < 4; ++i2) {
      const int r = r0 + quad * 4 + i2;
      dst[(size_t)r * NE + eb * 16 + m] = acc[eb][i2] * ds;
    }
  }
}

// ---------------------------------------------------------------------------
// reduces for the 4-sweep schedule (partials are already descaled).
// ---------------------------------------------------------------------------
__global__ __launch_bounds__(256)
void reduce_uA(const float* __restrict__ u_part, const float* __restrict__ u0,
               float* __restrict__ acc_u, u8* __restrict__ wT64)
{
  const int gid = blockIdx.x * 256 + threadIdx.x;     // U_N*32
  float s = 0.f;
#pragma unroll
  for (int sp = 0; sp < 8; ++sp) s += u_part[(size_t)sp * (U_N * 32) + gid];
  acc_u[gid] = u0[gid] + s;
  wT64[(size_t)(32 + (gid & 31)) * U_N + (gid >> 5)] = q8(s * SCALE_VK);
}

__global__ __launch_bounds__(256)
void reduce_iB(const float* __restrict__ i_part, const float* __restrict__ i0,
               float* __restrict__ acc_i, u8* __restrict__ vT64)
{
  const int gid = blockIdx.x * 256 + threadIdx.x;     // I_N*32
  const int c = gid >> 5, e = gid & 31;
  float s1 = 0.f, s2 = 0.f;
#pragma unroll
  for (int sp = 0; sp < 4; ++sp) {
    s1 += i_part[(size_t)sp * (I_N * 64) + (size_t)c * 64 + e];
    s2 += i_part[(size_t)sp * (I_N * 64) + (size_t)c * 64 + 32 + e];
  }
  acc_i[gid] = i0[gid] + s1 + s2;
  vT64[(size_t)e * I_N + c]        = q8(s1 * SCALE_VK);
  vT64[(size_t)(32 + e) * I_N + c] = q8(s2 * SCALE_VK);
}

__global__ __launch_bounds__(256)
void reduce_uC(const float* __restrict__ u_part, const float* __restrict__ acc_u,
               float* __restrict__ out_u, u8* __restrict__ wT2)
{
  const int gid = blockIdx.x * 256 + threadIdx.x;     // U_N*32
  const int r = gid >> 5, e = gid & 31;
  float s2 = 0.f, s3 = 0.f;
#pragma unroll
  for (int sp = 0; sp < 8; ++sp) {
    s2 += u_part[(size_t)sp * (U_N * 64) + (size_t)r * 64 + e];
    s3 += u_part[(size_t)sp * (U_N * 64) + (size_t)r * 64 + 32 + e];
  }
  out_u[gid] = (acc_u[gid] + s2 + s3) * 0.25f;
  wT2[(size_t)e * U_N + r] = q8(s2 * SCALE_VK);
}

__global__ __launch_bounds__(256)
void reduce_iD(const float* __restrict__ i_part, const float* __restrict__ acc_i,
               float* __restrict__ out_i)
{
  const int gid = blockIdx.x * 256 + threadIdx.x;     // I_N*32
  float s = 0.f;
#pragma unroll
  for (int sp = 0; sp < 4; ++sp) s += i_part[(size_t)sp * (I_N * 32) + gid];
  out_i[gid] = (acc_i[gid] + s) * 0.25f;
}

// ---------------------------------------------------------------------------
// fallback (small workspace): original fp32-based 3-round pipeline.
// ---------------------------------------------------------------------------
__global__ __launch_bounds__(256, 4)
void pass_fallback(const float* __restrict__ Sf,
                   const u8* __restrict__ vT,
                   const u8* __restrict__ wT,
                   float* __restrict__ u_part,
                   float* __restrict__ i_part,
                   float descale)
{
  __shared__ unsigned char smem[16896];
  const int tid = threadIdx.x;
  const int lane = tid & 63;
  const int wave = tid >> 6;
  const int m = lane & 15;
  const int quad = lane >> 4;
  const int bid = blockIdx.x;

  if (bid < 1024) {
    const int rg = bid & 127, ks = bid >> 7;
    const int r0 = rg * 64 + wave * 16;
    const int cbase = ks * 2048;
    f4 acc0 = {0.f, 0.f, 0.f, 0.f};
    f4 acc1 = {0.f, 0.f, 0.f, 0.f};
    for (int ch = 0; ch < 4; ++ch) {
      const int cb = cbase + ch * 512;
#pragma unroll
      for (int it = 0; it < 4; ++it) {
        const int idx = it * 256 + tid;
        const int e = idx >> 5;
        const int o = (idx & 31) * 16;
        *(uint4*)&smem[e * 528 + o] = *(const uint4*)&vT[(size_t)e * I_N + cb + o];
      }
      __syncthreads();
#pragma unroll
      for (int kk = 0; kk < 512; kk += 32) {
        const float* p = Sf + (size_t)(r0 + m) * I_N + cb + kk + quad * 8;
        u64 av = 0;
#pragma unroll
        for (int j = 0; j < 8; ++j) av |= (u64)q8(p[j] * SCALE_S) << (8 * j);
        const long a = (long)av;
        const long b0 = *(const long*)&smem[m * 528 + kk + quad * 8];
        const long b1 = *(const long*)&smem[(m + 16) * 528 + kk + quad * 8];
        acc0 = __builtin_amdgcn_mfma_f32_16x16x32_fp8_fp8(a, b0, acc0, 0, 0, 0);
        acc1 = __builtin_amdgcn_mfma_f32_16x16x32_fp8_fp8(a, b1, acc1, 0, 0, 0);
      }
      __syncthreads();
    }
    float* dst = u_part + (size_t)ks * (U_N * 32);
#pragma unroll
    for (int i2 = 0; i2 < 4; ++i2) {
      const int r = r0 + quad * 4 + i2;
      dst[r * 32 + m]      = acc0[i2] * descale;
      dst[r * 32 + 16 + m] = acc1[i2] * descale;
    }
  } else {
    const int b = bid - 1024;
    const int cg = b & 255, rs = b >> 8;
    const int c0 = cg * 64;
    const int rbase = rs * 2048;
    const int cw = wave * 16;
    unsigned char* stile = smem;
    unsigned char* wlds  = smem + 9216;
    f4 acc0 = {0.f, 0.f, 0.f, 0.f};
    f4 acc1 = {0.f, 0.f, 0.f, 0.f};
    for (int ch = 0; ch < 16; ++ch) {
      const int rb = rbase + ch * 128;
#pragma unroll
      for (int it = 0; it < 4; ++it) {
        const int idx = it * 256 + tid;
        const int rr = idx >> 3;
        const int o = (idx & 7) * 8;
        const float* p = Sf + (size_t)(rb + rr) * I_N + c0 + o;
        u64 v = 0;
#pragma unroll
        for (int j = 0; j < 8; ++j) v |= (u64)q8(p[j] * SCALE_S) << (8 * j);
        *(u64*)&stile[rr * 72 + o] = v;
      }
      {
        const int e = tid >> 3;
        const int o = (tid & 7) * 16;
        *(uint4*)&wlds[e * 144 + o] = *(const uint4*)&wT[(size_t)e * U_N + rb + o];
      }
      __syncthreads();
#pragma unroll
      for (int kk = 0; kk < 128; kk += 32) {
        u64 av = 0;
#pragma unroll
        for (int j = 0; j < 8; ++j)
          av |= (u64)stile[(kk + quad * 8 + j) * 72 + cw + m] << (8 * j);
        const long b0 = *(const long*)&wlds[m * 144 + kk + quad * 8];
        const long b1 = *(const long*)&wlds[(m + 16) * 144 + kk + quad * 8];
        acc0 = __builtin_amdgcn_mfma_f32_16x16x32_fp8_fp8((long)av, b0, acc0, 0, 0, 0);
        acc1 = __builtin_amdgcn_mfma_f32_16x16x32_fp8_fp8((long)av, b1, acc1, 0, 0, 0);
      }
      __syncthreads();
    }
    float* dst = i_part + (size_t)rs * (I_N * 32);
#pragma unroll
    for (int i2 = 0; i2 < 4; ++i2) {
      const int c = c0 + cw + quad * 4 + i2;
      dst[c * 32 + m]      = acc0[i2] * descale;
      dst[c * 32 + 16 + m] = acc1[i2] * descale;
    }
  }
}

__global__ __launch_bounds__(256)
void reduce_fallback(const float* __restrict__ u_part, const float* __restrict__ i_part,
                     const float* __restrict__ u0, const float* __restrict__ i0,
                     float* __restrict__ acc_u, float* __restrict__ acc_i,
                     u8* __restrict__ wT, u8* __restrict__ vT,
                     float* __restrict__ out_u, float* __restrict__ out_i,
                     int round)
{
  const int gid = blockIdx.x * 256 + threadIdx.x;
  if (gid < U_N * 32) {
    float s = 0.f;
#pragma unroll
    for (int sp = 0; sp < 8; ++sp) s += u_part[(size_t)sp * (U_N * 32) + gid];
    if (round == 1)      acc_u[gid] = u0[gid] + s;
    else if (round == 2) acc_u[gid] += s;
    else                 out_u[gid] = (acc_u[gid] + s) * 0.25f;
    if (round < 3) wT[(gid & 31) * U_N + (gid >> 5)] = q8(s * SCALE_VK);
  } else {
    const int g = gid - U_N * 32;
    float s = 0.f;
#pragma unroll
    for (int sp = 0; sp < 4; ++sp) s += i_part[(size_t)sp * (I_N * 32) + g];
    if (round == 1)      acc_i[g] = i0[g] + s;
    else if (round == 2) acc_i[g] += s;
    else                 out_i[g] = (acc_i[g] + s) * 0.25f;
    if (round < 3) vT[(g & 31) * I_N + (g >> 5)] = q8(s * SCALE_VK);
  }
}

extern "C" void kernel_launch(void* const* d_in, const int* in_sizes, int n_in,
                              void* d_out, int out_size, void* d_ws, size_t ws_size,
                              hipStream_t stream) {
  const float* u0 = (const float*)d_in[0];   // [8192][32]
  const float* i0 = (const float*)d_in[1];   // [16384][32]
  const float* Sf = (const float*)d_in[2];   // [8192][16384]
  float* out_u = (float*)d_out;
  float* out_i = out_u + U_N * 32;
  u8* ws = (u8*)d_ws;

  const size_t S8B = (size_t)U_N * I_N;                 // 128 MB each
  const size_t FULL_BYTES = 2 * S8B                     // S8 + S8T
      + (size_t)8 * U_N * 64 * 4 + (size_t)4 * I_N * 64 * 4   // partials
      + (size_t)U_N * 32 * 4 + (size_t)I_N * 32 * 4           // accs
      + (size_t)64 * U_N + (size_t)64 * I_N                   // wT64, vT64
      + (size_t)32 * I_N + (size_t)32 * U_N;                  // vT0, wT2
  const bool f8 = ws_size >= FULL_BYTES;

  const float dsA = 1.f / (SCALE_S * SCALE_V0);
  const float dsk = 1.f / (SCALE_S * SCALE_VK);

  if (f8) {
    u8* S8  = ws;
    u8* S8T = ws + S8B;
    float* u_part = (float*)(ws + 2 * S8B);             // [8][U_N][64] max
    float* i_part = u_part + (size_t)8 * U_N * 64;      // [4][I_N][64] max
    float* acc_u  = i_part + (size_t)4 * I_N * 64;
    float* acc_i  = acc_u + U_N * 32;
    u8* wT64 = (u8*)(acc_i + I_N * 32);                 // [64][U_N]
    u8* vT64 = wT64 + (size_t)64 * U_N;                 // [64][I_N]
    u8* vT0  = vT64 + (size_t)64 * I_N;                 // [32][I_N]
    u8* wT2  = vT0 + (size_t)32 * I_N;                  // [32][U_N]

    convert_kernel<<<35840, 256, 0, stream>>>(Sf, u0, i0, S8, S8T, wT64, vT0);

    // sweep A: u1 = S i0
    sweep_kernel<32><<<1024, 256, 0, stream>>>(S8, vT0, u_part, 127, 7,
                                               U_N, I_N, dsA, dsA);
    reduce_uA<<<1024, 256, 0, stream>>>(u_part, u0, acc_u, wT64);
    // sweep B: [i1|i2] = S^T [u0|u1]
    sweep_kernel<64><<<1024, 256, 0, stream>>>(S8T, wT64, i_part, 255, 8,
                                               I_N, U_N, dsA, dsk);
    reduce_iB<<<2048, 256, 0, stream>>>(i_part, i0, acc_i, vT64);
    // sweep C: [u2|u3] = S [i1|i2]
    sweep_kernel<64><<<1024, 256, 0, stream>>>(S8, vT64, u_part, 127, 7,
                                               U_N, I_N, dsk, dsk);
    reduce_uC<<<1024, 256, 0, stream>>>(u_part, acc_u, out_u, wT2);
    // sweep D: i3 = S^T u2
    sweep_kernel<32><<<1024, 256, 0, stream>>>(S8T, wT2, i_part, 255, 8,
                                               I_N, U_N, dsk, dsk);
    reduce_iD<<<2048, 256, 0, stream>>>(i_part, acc_i, out_i);
  } else {
    // fp32 fallback, 3-round pipeline
    float* u_part = (float*)ws;                         // [8][U_N][32]
    float* i_part = u_part + 8 * U_N * 32;              // [4][I_N][32]
    float* acc_u  = i_part + 4 * I_N * 32;
    float* acc_i  = acc_u + U_N * 32;
    u8* wT = (u8*)(acc_i + I_N * 32);
    u8* vT = wT + 32 * U_N;

    convert_kernel<<<3072, 256, 0, stream>>>(Sf, u0, i0, nullptr, nullptr, wT, vT);
    for (int round = 1; round <= 3; ++round) {
      const float ds = (round == 1) ? dsA : dsk;
      pass_fallback<<<2048, 256, 0, stream>>>(Sf, vT, wT, u_part, i_part, ds);
      reduce_fallback<<<3072, 256, 0, stream>>>(u_part, i_part, u0, i0, acc_u, acc_i,
                                                wT, vT, out_u, out_i, round);
    }
  }
}